// Round 1
// baseline (304.061 us; speedup 1.0000x reference)
//
#include <hip/hip_runtime.h>

#define C_ 64
#define H_ 128
#define W_ 128
#define B_ 8
#define HW_ (H_*W_)
#define NPIX (B_*HW_)

// ---------------------------------------------------------------------------
// Kernel A: fused offset/mask convs for both passes + weight transposes.
// One thread per pixel. 5-point cross load per channel, 54 FMAs/channel.
// ---------------------------------------------------------------------------
__global__ __launch_bounds__(256) void offs_kernel(
    const float* __restrict__ x,
    const float* __restrict__ w_off_h, const float* __restrict__ b_off_h,
    const float* __restrict__ w_mask_h, const float* __restrict__ b_mask_h,
    const float* __restrict__ w_off_v, const float* __restrict__ b_off_v,
    const float* __restrict__ w_mask_v, const float* __restrict__ b_mask_v,
    const float* __restrict__ w_h, const float* __restrict__ w_v,
    float* __restrict__ off_h, float* __restrict__ mask_h,
    float* __restrict__ off_v, float* __restrict__ mask_v,
    float* __restrict__ wT_h, float* __restrict__ wT_v)
{
    int p = blockIdx.x * 256 + threadIdx.x;

    // Weight transpose: wT[c*192 + k*64 + o] = w[o*192 + c*3 + k]
    // (makes deform-kernel weight reads contiguous & wave-uniform -> s_load)
    if (p < 2 * 12288) {
        int which = p / 12288;
        int idx = p - which * 12288;
        int o = idx & 63;
        int ck = idx >> 6;
        int c = ck / 3;
        int k = ck - 3 * c;
        const float* srcw = which ? w_v : w_h;
        float* dstw = which ? wT_v : wT_h;
        dstw[idx] = srcw[o * 192 + c * 3 + k];
    }

    int j = p & (W_ - 1);
    int i = (p >> 7) & (H_ - 1);
    int n = p >> 14;
    int pix = i * W_ + j;

    float aoh[6], amh[3], aov[6], amv[3];
    #pragma unroll
    for (int o = 0; o < 6; ++o) { aoh[o] = b_off_h[o]; aov[o] = b_off_v[o]; }
    #pragma unroll
    for (int o = 0; o < 3; ++o) { amh[o] = b_mask_h[o]; amv[o] = b_mask_v[o]; }

    const float* xb = x + (size_t)n * C_ * HW_;
    for (int c = 0; c < C_; ++c) {
        const float* s = xb + c * HW_;
        float xc = s[pix];
        float xl = (j > 0)      ? s[pix - 1]  : 0.f;
        float xr = (j < W_ - 1) ? s[pix + 1]  : 0.f;
        float xu = (i > 0)      ? s[pix - W_] : 0.f;
        float xd = (i < H_ - 1) ? s[pix + W_] : 0.f;
        const float* wh = w_off_h  + c * 3;
        const float* wm = w_mask_h + c * 3;
        const float* wv = w_off_v  + c * 3;
        const float* wn = w_mask_v + c * 3;
        #pragma unroll
        for (int o = 0; o < 6; ++o) {
            aoh[o] = fmaf(xl, wh[o*192+0], fmaf(xc, wh[o*192+1], fmaf(xr, wh[o*192+2], aoh[o])));
            aov[o] = fmaf(xu, wv[o*192+0], fmaf(xc, wv[o*192+1], fmaf(xd, wv[o*192+2], aov[o])));
        }
        #pragma unroll
        for (int o = 0; o < 3; ++o) {
            amh[o] = fmaf(xl, wm[o*192+0], fmaf(xc, wm[o*192+1], fmaf(xr, wm[o*192+2], amh[o])));
            amv[o] = fmaf(xu, wn[o*192+0], fmaf(xc, wn[o*192+1], fmaf(xd, wn[o*192+2], amv[o])));
        }
    }
    #pragma unroll
    for (int o = 0; o < 6; ++o) {
        off_h[((size_t)n * 6 + o) * HW_ + pix] = aoh[o];
        off_v[((size_t)n * 6 + o) * HW_ + pix] = aov[o];
    }
    #pragma unroll
    for (int o = 0; o < 3; ++o) {
        mask_h[((size_t)n * 3 + o) * HW_ + pix] = 1.f / (1.f + __expf(-amh[o]));
        mask_v[((size_t)n * 3 + o) * HW_ + pix] = 1.f / (1.f + __expf(-amv[o]));
    }
}

// ---------------------------------------------------------------------------
// Kernel B/C: deformable axial conv pass.
// One thread per pixel (lane = consecutive j -> coalesced gathers).
// 64 fp32 accumulators in VGPRs; weights read wave-uniform from wT (scalar).
// axis=0: taps along x (horizontal pass); axis=1: taps along y (vertical).
// ---------------------------------------------------------------------------
__global__ __launch_bounds__(256) void deform_kernel(
    const float* __restrict__ src, const float* __restrict__ off,
    const float* __restrict__ mask, const float* __restrict__ wT,
    const float* __restrict__ bias, float* __restrict__ out, int axis)
{
    int p = blockIdx.x * 256 + threadIdx.x;
    int j = p & (W_ - 1);
    int i = (p >> 7) & (H_ - 1);
    int n = p >> 14;
    int pix = i * W_ + j;

    int a00[3], a01[3], a10[3], a11[3];
    float w00[3], w01[3], w10[3], w11[3];

    #pragma unroll
    for (int k = 0; k < 3; ++k) {
        float dy = off[(((size_t)n * 3 + k) * 2 + 0) * HW_ + pix];
        float dx = off[(((size_t)n * 3 + k) * 2 + 1) * HW_ + pix];
        float m  = mask[((size_t)n * 3 + k) * HW_ + pix];
        float py = (float)i + dy + (axis ? (float)(k - 1) : 0.f);
        float px = (float)j + dx + (axis ? 0.f : (float)(k - 1));
        float y0f = floorf(py), x0f = floorf(px);
        float wy = py - y0f, wx = px - x0f;
        int y0 = (int)y0f, x0 = (int)x0f;
        int y1 = y0 + 1, x1 = x0 + 1;
        bool vy0 = (y0 >= 0) && (y0 < H_);
        bool vy1 = (y1 >= 0) && (y1 < H_);
        bool vx0 = (x0 >= 0) && (x0 < W_);
        bool vx1 = (x1 >= 0) && (x1 < W_);
        int y0c = min(max(y0, 0), H_ - 1), y1c = min(max(y1, 0), H_ - 1);
        int x0c = min(max(x0, 0), W_ - 1), x1c = min(max(x1, 0), W_ - 1);
        a00[k] = y0c * W_ + x0c;  a01[k] = y0c * W_ + x1c;
        a10[k] = y1c * W_ + x0c;  a11[k] = y1c * W_ + x1c;
        float wy1 = 1.f - wy, wx1 = 1.f - wx;
        w00[k] = (vy0 && vx0) ? wy1 * wx1 * m : 0.f;
        w01[k] = (vy0 && vx1) ? wy1 * wx  * m : 0.f;
        w10[k] = (vy1 && vx0) ? wy  * wx1 * m : 0.f;
        w11[k] = (vy1 && vx1) ? wy  * wx  * m : 0.f;
    }

    float acc[64];
    #pragma unroll
    for (int o = 0; o < 64; ++o) acc[o] = 0.f;

    const float* sb = src + (size_t)n * C_ * HW_;
    for (int c = 0; c < C_; ++c) {
        const float* s = sb + c * HW_;
        float vk[3];
        #pragma unroll
        for (int k = 0; k < 3; ++k) {
            vk[k] = fmaf(w00[k], s[a00[k]],
                    fmaf(w01[k], s[a01[k]],
                    fmaf(w10[k], s[a10[k]],
                         w11[k] * s[a11[k]])));
        }
        const float* wr = wT + c * 192;
        #pragma unroll
        for (int o = 0; o < 64; ++o) {
            acc[o] = fmaf(vk[0], wr[o],
                     fmaf(vk[1], wr[64 + o],
                     fmaf(vk[2], wr[128 + o], acc[o])));
        }
    }

    float* op = out + (size_t)n * C_ * HW_ + pix;
    #pragma unroll
    for (int o = 0; o < 64; ++o)
        op[(size_t)o * HW_] = acc[o] + bias[o];
}

// ---------------------------------------------------------------------------
extern "C" void kernel_launch(void* const* d_in, const int* in_sizes, int n_in,
                              void* d_out, int out_size, void* d_ws, size_t ws_size,
                              hipStream_t stream)
{
    const float* x        = (const float*)d_in[0];
    const float* w_off_h  = (const float*)d_in[1];
    const float* b_off_h  = (const float*)d_in[2];
    const float* w_mask_h = (const float*)d_in[3];
    const float* b_mask_h = (const float*)d_in[4];
    const float* w_off_v  = (const float*)d_in[5];
    const float* b_off_v  = (const float*)d_in[6];
    const float* w_mask_v = (const float*)d_in[7];
    const float* b_mask_v = (const float*)d_in[8];
    const float* w_h      = (const float*)d_in[9];
    const float* b_h      = (const float*)d_in[10];
    const float* w_v      = (const float*)d_in[11];
    const float* b_v      = (const float*)d_in[12];

    float* ws     = (float*)d_ws;
    float* off_h  = ws;                   // 786432
    float* mask_h = off_h  + 786432;      // 393216
    float* off_v  = mask_h + 393216;      // 786432
    float* mask_v = off_v  + 786432;      // 393216
    float* x_h    = mask_v + 393216;      // 8388608
    float* wT_h   = x_h    + 8388608;     // 12288
    float* wT_v   = wT_h   + 12288;       // 12288
    // total: 10,772,480 floats = ~43.1 MB of d_ws

    dim3 grid(NPIX / 256), block(256);
    offs_kernel<<<grid, block, 0, stream>>>(x,
        w_off_h, b_off_h, w_mask_h, b_mask_h,
        w_off_v, b_off_v, w_mask_v, b_mask_v,
        w_h, w_v,
        off_h, mask_h, off_v, mask_v, wT_h, wT_v);

    deform_kernel<<<grid, block, 0, stream>>>(x,   off_h, mask_h, wT_h, b_h, x_h,          0);
    deform_kernel<<<grid, block, 0, stream>>>(x_h, off_v, mask_v, wT_v, b_v, (float*)d_out, 1);
}